// Round 11
// baseline (116.081 us; speedup 1.0000x reference)
//
#include <hip/hip_runtime.h>
#include <hip/hip_bf16.h>
#include <stdint.h>

#define NB 8
#define DIMG 2048
#define HWN 196
#define PN 1568
#define PPAD 1600
#define DMID 1024
#define NC 80
#define DWORD 300
#define PART 8

typedef short bf16x8 __attribute__((ext_vector_type(8)));
typedef float f32x4 __attribute__((ext_vector_type(4)));

__device__ __forceinline__ unsigned short f2bf(float x) {
  union { float f; unsigned u; } c; c.f = x;
  unsigned r = c.u + 0x7FFFu + ((c.u >> 16) & 1u);
  return (unsigned short)(r >> 16);
}
__device__ __forceinline__ float bflo(unsigned u) {
  union { unsigned v; float f; } c; c.v = u << 16; return c.f;
}
__device__ __forceinline__ float bfhi(unsigned u) {
  union { unsigned v; float f; } c; c.v = u & 0xffff0000u; return c.f;
}

// ---------------------------------------------------------------- transpose (bf16 only) + W1 cvt
__global__ void k_tc(const float* __restrict__ img, unsigned short* __restrict__ fmapH,
                     const float* __restrict__ W1, unsigned short* __restrict__ W1h) {
  __shared__ float tile[32][33];
  int bx = blockIdx.x;
  int tx = threadIdx.x, ty = threadIdx.y;
  if (bx < 3584) {
    int d0 = (bx & 63) * 32;
    int rem = bx >> 6;
    int h0 = (rem % 7) * 32, b = rem / 7;
    const float* src = img + (size_t)b * DIMG * HWN;
#pragma unroll
    for (int i = 0; i < 32; i += 8) {
      int hw = h0 + tx;
      tile[ty + i][tx] = (hw < HWN) ? src[(size_t)(d0 + ty + i) * HWN + hw] : 0.f;
    }
    __syncthreads();
#pragma unroll
    for (int i = 0; i < 32; i += 8) {
      int hw = h0 + ty + i;
      if (hw < HWN)
        fmapH[(size_t)(b * HWN + hw) * DIMG + d0 + tx] = f2bf(tile[tx][ty + i]);
    }
  } else {
    int tid = ty * 32 + tx;
    int i = ((bx - 3584) * 256 + tid) * 4;
    f32x4 v = *(const f32x4*)(W1 + i);
    ushort4 s;
    s.x = f2bf(v[0]); s.y = f2bf(v[1]); s.z = f2bf(v[2]); s.w = f2bf(v[3]);
    *(ushort4*)(W1h + i) = s;
  }
}

// ---------------------------------------------------------------- fwd + weff (coalesced, LDS-staged)
// fwd[c][m] = SC * sum_k word[c][k]*W2[m][k]  (SC = 2*log2e)
__global__ __launch_bounds__(256) void k_fwdweff(const float* __restrict__ word,
                                                 const float* __restrict__ W2,
                                                 float* __restrict__ fwd,
                                                 const float* __restrict__ Wa,
                                                 const float* __restrict__ W3,
                                                 float* __restrict__ partial) {
  __shared__ __align__(16) float w2s[64 * DWORD];   // 76.8 KB
  __shared__ __align__(16) float wds[16 * DWORD];   // 19.2 KB
  int bx = blockIdx.x, t = threadIdx.x;
  if (bx < 80) {
    int m0 = (bx & 15) * 64, c0 = (bx >> 4) * 16;
    const float SC = 2.8853900817779268f;  // 2*log2(e)
    for (int u = t; u < 64 * 75; u += 256) {
      int r = u / 75, q = u - r * 75;
      *(f32x4*)&w2s[r * DWORD + q * 4] =
          *(const f32x4*)(W2 + (size_t)(m0 + r) * DWORD + q * 4);
    }
    for (int u = t; u < 16 * 75; u += 256) {
      int r = u / 75, q = u - r * 75;
      f32x4 v = *(const f32x4*)(word + (size_t)(c0 + r) * DWORD + q * 4);
      *(f32x4*)&wds[r * DWORD + q * 4] = v * SC;
    }
    __syncthreads();
    int ci = t >> 4, mi = t & 15;
    f32x4 a0 = {0.f, 0.f, 0.f, 0.f}, a1 = a0, a2 = a0, a3 = a0;
    const float* wr = &wds[ci * DWORD];
    for (int q = 0; q < 75; ++q) {
      f32x4 wv = *(const f32x4*)&wr[q * 4];
      f32x4 b0 = *(const f32x4*)&w2s[(mi)*DWORD + q * 4];
      f32x4 b1 = *(const f32x4*)&w2s[(mi + 16) * DWORD + q * 4];
      f32x4 b2 = *(const f32x4*)&w2s[(mi + 32) * DWORD + q * 4];
      f32x4 b3 = *(const f32x4*)&w2s[(mi + 48) * DWORD + q * 4];
#pragma unroll
      for (int u = 0; u < 4; ++u) {
        a0[u] = fmaf(wv[u], b0[u], a0[u]);
        a1[u] = fmaf(wv[u], b1[u], a1[u]);
        a2[u] = fmaf(wv[u], b2[u], a2[u]);
        a3[u] = fmaf(wv[u], b3[u], a3[u]);
      }
    }
    float* dst = fwd + (size_t)(c0 + ci) * DMID + m0 + mi;
    dst[0]  = a0[0] + a0[1] + a0[2] + a0[3];
    dst[16] = a1[0] + a1[1] + a1[2] + a1[3];
    dst[32] = a2[0] + a2[1] + a2[2] + a2[3];
    dst[48] = a3[0] + a3[1] + a3[2] + a3[3];
  } else {
    int idx = bx - 80;
    int m = (idx & 3) * 256 + t;
    int n0 = (idx >> 2) * 64;
    float acc = 0.f;
    for (int n = n0; n < n0 + 64; ++n) acc = fmaf(Wa[n], W3[(size_t)n * DMID + m], acc);
    partial[(size_t)(idx >> 2) * DMID + m] = acc;
  }
}

// ---------------------------------------------------------------- FUSED, software-pipelined:
// block (px, mg): 2 m-chunks (64 each). Phase1: MFMA chunkA -> X0.
// Phase2: MFMA chunkB K-loop with sigmoid(X0) interleaved (2 m / K-step).
// Phase3: sigmoid(X1). Both chunks accumulate into same sacc -> coefp[mg].
#define GLDS(g, l) \
  __builtin_amdgcn_global_load_lds((const __attribute__((address_space(1))) void*)(g), \
                                   (__attribute__((address_space(3))) void*)(l), 16, 0, 0)

__global__ __launch_bounds__(256) void k_fused(const unsigned short* __restrict__ A,
                                               const unsigned short* __restrict__ Bw,
                                               const float* __restrict__ fwd,
                                               const float* __restrict__ partial,
                                               float* __restrict__ coefp) {
  __shared__ __align__(16) char smem[76544];           // 74.75 KB -> 2 blocks/CU
  unsigned short* As = (unsigned short*)smem;          // [3][2048] ushort (12 KB)
  unsigned short* Bs = As + 3 * 2048;                  // [3][4096] ushort (24 KB)
  float* Xl0 = (float*)(smem + 36864);                 // [32][68] f32 (8.7 KB)
  float* Xl1 = (float*)(smem + 45568);                 // [32][68] f32 (8.7 KB)
  unsigned short* bl = (unsigned short*)(smem + 54272);// [80][136] bf16 (21.8 KB)
  float* wl = (float*)(smem + 76032);                  // [128] f32
  int p0 = blockIdx.x * 32;
  int n0 = blockIdx.y * 128;
  int t = threadIdx.x;
  int w = t >> 6, l = t & 63;
  int pi = t >> 4, ci = t & 15;

  // ---- prologue: bl (bf16, prescaled fwd slice 80x128), wl (-2*sum partial)
#pragma unroll
  for (int i = 0; i < 10; ++i) {
    int g = t + 256 * i;                 // 2560 f32x4 groups
    int row = g >> 5, c4 = (g & 31) << 2;
    f32x4 v = *(const f32x4*)(fwd + (size_t)row * DMID + n0 + c4);
    ushort4 h;
    h.x = f2bf(v[0]); h.y = f2bf(v[1]); h.z = f2bf(v[2]); h.w = f2bf(v[3]);
    *(ushort4*)&bl[row * 136 + c4] = h;
  }
  if (t < 128) {
    float v = 0.f;
#pragma unroll
    for (int s = 0; s < 16; ++s) v += partial[(size_t)s * DMID + n0 + t];
    wl[t] = -2.f * v;
  }

  // staging pointers (pre-swizzled global source, linear LDS dest)
  int r0 = t >> 3, cch = t & 7;
  int r1 = r0 + 32;
  const unsigned short* gA   = A  + (size_t)(p0 + r0) * 2048 + ((cch ^ (r0 & 7)) << 3);
  const unsigned short* gB0a = Bw + (size_t)(n0 + r0) * 2048 + ((cch ^ (r0 & 7)) << 3);
  const unsigned short* gB1a = Bw + (size_t)(n0 + r1) * 2048 + ((cch ^ (r1 & 7)) << 3);
  const unsigned short* gB0b = gB0a + 64 * 2048;
  const unsigned short* gB1b = gB1a + 64 * 2048;

  // frag read offsets (swizzled)
  int ra = l & 15;
  int rb = w * 16 + (l & 15);
  int cc = l >> 4;
  int a_k0 = ra * 64 + (((cc) ^ (ra & 7)) << 3);
  int a_k1 = ra * 64 + (((cc + 4) ^ (ra & 7)) << 3);
  int b_k0 = rb * 64 + (((cc) ^ (rb & 7)) << 3);
  int b_k1 = rb * 64 + (((cc + 4) ^ (rb & 7)) << 3);

#define STAGEA(bi, kk) do { \
    GLDS(gA + (kk), As + (bi) * 2048 + t * 8); \
    GLDS(gB0a + (kk), Bs + (bi) * 4096 + t * 8); \
    GLDS(gB1a + (kk), Bs + (bi) * 4096 + t * 8 + 2048); \
  } while (0)
#define STAGEB(bi, kk) do { \
    GLDS(gA + (kk), As + (bi) * 2048 + t * 8); \
    GLDS(gB0b + (kk), Bs + (bi) * 4096 + t * 8); \
    GLDS(gB1b + (kk), Bs + (bi) * 4096 + t * 8 + 2048); \
  } while (0)
#define COMPUTE(bi, c0v, c1v) do { \
    const unsigned short* ap = As + (bi) * 2048; \
    const unsigned short* bp = Bs + (bi) * 4096; \
    bf16x8 A0 = *(const bf16x8*)(ap + a_k0); \
    bf16x8 A1 = *(const bf16x8*)(ap + a_k0 + 1024); \
    bf16x8 B0 = *(const bf16x8*)(bp + b_k0); \
    __builtin_amdgcn_s_setprio(1); \
    c0v = __builtin_amdgcn_mfma_f32_16x16x32_bf16(A0, B0, c0v, 0, 0, 0); \
    c1v = __builtin_amdgcn_mfma_f32_16x16x32_bf16(A1, B0, c1v, 0, 0, 0); \
    __builtin_amdgcn_s_setprio(0); \
    bf16x8 A2 = *(const bf16x8*)(ap + a_k1); \
    bf16x8 A3 = *(const bf16x8*)(ap + a_k1 + 1024); \
    bf16x8 B1 = *(const bf16x8*)(bp + b_k1); \
    __builtin_amdgcn_s_setprio(1); \
    c0v = __builtin_amdgcn_mfma_f32_16x16x32_bf16(A2, B1, c0v, 0, 0, 0); \
    c1v = __builtin_amdgcn_mfma_f32_16x16x32_bf16(A3, B1, c1v, 0, 0, 0); \
    __builtin_amdgcn_s_setprio(0); \
  } while (0)
// sigmoid pair: 2 m's at column m_ of X-tile XP, bl/wl offset moff
#define SIG2(XP, mcol, moff) do { \
    int m_ = (mcol); \
    float wg0 = wl[(moff) + m_], wg1 = wl[(moff) + m_ + 1]; \
    float a00 = XP[pi * 68 + m_],        a01 = XP[pi * 68 + m_ + 1]; \
    float a10 = XP[(pi + 16) * 68 + m_], a11 = XP[(pi + 16) * 68 + m_ + 1]; \
    _Pragma("unroll") \
    for (int k_ = 0; k_ < 5; ++k_) { \
      unsigned bb = *(const unsigned*)&bl[(k_ * 16 + ci) * 136 + (moff) + m_]; \
      float b0 = bflo(bb), b1 = bfhi(bb); \
      float e00 = __builtin_amdgcn_exp2f(a00 * b0); \
      float e01 = __builtin_amdgcn_exp2f(a01 * b1); \
      float e10 = __builtin_amdgcn_exp2f(a10 * b0); \
      float e11 = __builtin_amdgcn_exp2f(a11 * b1); \
      sacc[0][k_] = fmaf(wg0, __builtin_amdgcn_rcpf(1.f + e00), sacc[0][k_]); \
      sacc[0][k_] = fmaf(wg1, __builtin_amdgcn_rcpf(1.f + e01), sacc[0][k_]); \
      sacc[1][k_] = fmaf(wg0, __builtin_amdgcn_rcpf(1.f + e10), sacc[1][k_]); \
      sacc[1][k_] = fmaf(wg1, __builtin_amdgcn_rcpf(1.f + e11), sacc[1][k_]); \
    } \
  } while (0)

  float sacc[2][5];
#pragma unroll
  for (int j = 0; j < 2; ++j)
#pragma unroll
    for (int k = 0; k < 5; ++k) sacc[j][k] = 0.f;

  f32x4 zero = {0.f, 0.f, 0.f, 0.f};
  f32x4 acc0 = zero, acc1 = zero;

  // ---- phase 1: MFMA chunk A
  STAGEA(0, 0);
  STAGEA(1, 64);
  __syncthreads();   // drains prologue vmem + bl/wl ds_writes; bufs 0,1 landed
  for (int kt = 0; kt < 32; ++kt) {
    if (kt < 30) STAGEA((kt + 2) % 3, (kt + 2) * 64);
    COMPUTE(kt % 3, acc0, acc1);
    if (kt < 30) {
      asm volatile("s_waitcnt vmcnt(3)" ::: "memory");
      __builtin_amdgcn_s_barrier();
      __builtin_amdgcn_sched_barrier(0);
    } else if (kt == 30) {
      asm volatile("s_waitcnt vmcnt(0)" ::: "memory");
      __builtin_amdgcn_s_barrier();
      __builtin_amdgcn_sched_barrier(0);
    }
  }
  // write X0
  {
    int xr = (l >> 4) << 2, xc = w * 16 + (l & 15);
#pragma unroll
    for (int q = 0; q < 4; ++q) {
      Xl0[(xr + q) * 68 + xc]      = acc0[q];
      Xl0[(xr + q + 16) * 68 + xc] = acc1[q];
    }
  }
  __syncthreads();

  // ---- phase 2: MFMA chunk B + sigmoid(X0) interleaved
  acc0 = zero; acc1 = zero;
  STAGEB(0, 0);
  STAGEB(1, 64);
  asm volatile("s_waitcnt vmcnt(3)" ::: "memory");
  __builtin_amdgcn_s_barrier();
  __builtin_amdgcn_sched_barrier(0);
  for (int kt = 0; kt < 32; ++kt) {
    if (kt < 30) STAGEB((kt + 2) % 3, (kt + 2) * 64);
    COMPUTE(kt % 3, acc0, acc1);
    SIG2(Xl0, 2 * kt, 0);
    if (kt < 30) {
      asm volatile("s_waitcnt vmcnt(3)" ::: "memory");
      __builtin_amdgcn_s_barrier();
      __builtin_amdgcn_sched_barrier(0);
    } else if (kt == 30) {
      asm volatile("s_waitcnt vmcnt(0)" ::: "memory");
      __builtin_amdgcn_s_barrier();
      __builtin_amdgcn_sched_barrier(0);
    }
  }
  // write X1
  {
    int xr = (l >> 4) << 2, xc = w * 16 + (l & 15);
#pragma unroll
    for (int q = 0; q < 4; ++q) {
      Xl1[(xr + q) * 68 + xc]      = acc0[q];
      Xl1[(xr + q + 16) * 68 + xc] = acc1[q];
    }
  }
  __syncthreads();

  // ---- phase 3: sigmoid(X1)
#pragma unroll 1
  for (int mm = 0; mm < 64; mm += 2) SIG2(Xl1, mm, 64);

  // ---- store
  float* cp = coefp + (size_t)blockIdx.y * (PN * NC);
#pragma unroll
  for (int j = 0; j < 2; ++j) {
    int p = p0 + pi + 16 * j;
    if (p < PN) {
#pragma unroll
      for (int k = 0; k < 5; ++k)
        cp[(size_t)p * NC + k * 16 + ci] = sacc[j][k];
    }
  }
#undef STAGEA
#undef STAGEB
#undef COMPUTE
#undef SIG2
}

// ---------------------------------------------------------------- softmax + pooling; sums 8 coef partials
__global__ __launch_bounds__(256) void k_pool(const float* __restrict__ coefp,
                                              const float* __restrict__ img,
                                              float* __restrict__ out) {
  __shared__ __align__(16) float wt[HWN][16];
  __shared__ float red[16][16];
  __shared__ float mxs[16], inv[16];
  int dc = blockIdx.x * 256, cg = blockIdx.y * 16, b = blockIdx.z;
  int t = threadIdx.x;
  for (int i = t; i < HWN * 4; i += 256) {
    int hw = i >> 2, j4 = (i & 3) << 2;
    size_t o = (size_t)(b * HWN + hw) * NC + cg + j4;
    f32x4 s = {0.f, 0.f, 0.f, 0.f};
#pragma unroll
    for (int z = 0; z < PART; ++z) s += *(const f32x4*)&coefp[o + (size_t)z * (PN * NC)];
    *(f32x4*)&wt[hw][j4] = s;
  }
  __syncthreads();
  int j = t & 15, g = t >> 4;
  float pm = -1e30f;
  for (int hw = g; hw < HWN; hw += 16) pm = fmaxf(pm, wt[hw][j]);
  red[g][j] = pm;
  __syncthreads();
  if (t < 16) {
    float m = red[0][t];
#pragma unroll
    for (int g2 = 1; g2 < 16; ++g2) m = fmaxf(m, red[g2][t]);
    mxs[t] = m;
  }
  __syncthreads();
  float mj = mxs[j], ps = 0.f;
  for (int hw = g; hw < HWN; hw += 16) {
    float e = __builtin_amdgcn_exp2f((wt[hw][j] - mj) * 1.4426950408889634f);
    wt[hw][j] = e;
    ps += e;
  }
  red[g][j] = ps;
  __syncthreads();
  if (t < 16) {
    float s = 0.f;
#pragma unroll
    for (int g2 = 0; g2 < 16; ++g2) s += red[g2][t];
    inv[t] = 1.f / s;
  }
  __syncthreads();
  float acc[16];
#pragma unroll
  for (int q = 0; q < 16; ++q) acc[q] = 0.f;
  const float* fpd = img + ((size_t)b * DIMG + dc + t) * HWN;
  for (int hw = 0; hw < HWN; ++hw) {
    float v = fpd[hw];
#pragma unroll
    for (int q = 0; q < 16; ++q) acc[q] = fmaf(wt[hw][q], v, acc[q]);
  }
#pragma unroll
  for (int q = 0; q < 16; ++q)
    out[((size_t)b * NC + cg + q) * DIMG + dc + t] = acc[q] * inv[q];
}

// ----------------------------------------------------------------
extern "C" void kernel_launch(void* const* d_in, const int* in_sizes, int n_in,
                              void* d_out, int out_size, void* d_ws, size_t ws_size,
                              hipStream_t stream) {
  const float* img  = (const float*)d_in[1];
  const float* word = (const float*)d_in[2];
  const float* W1   = (const float*)d_in[3];
  const float* W2   = (const float*)d_in[4];
  const float* W3   = (const float*)d_in[5];
  const float* Wa   = (const float*)d_in[7];
  // b3 (d_in[6]) and ba (d_in[8]) are softmax-shift-invariant -> dropped.
  float* out = (float*)d_out;
  char* ws = (char*)d_ws;

  unsigned short* fmapH   = (unsigned short*)(ws + 0);         // 1600*2048*2 = 6,553,600
  unsigned short* W1h     = (unsigned short*)(ws + 6553600);   // 1024*2048*2 = 4,194,304
  float*          fwd     = (float*)(ws + 10747904);           //  96*1024*4 =   393,216
  float*          partial = (float*)(ws + 11141120);           //  16*1024*4 =    65,536
  float*          coefp   = (float*)(ws + 11206656);           // 8*1568*80*4 = 4,014,080

  hipLaunchKernelGGL(k_tc, dim3(5632), dim3(32, 8), 0, stream, img, fmapH, W1, W1h);
  hipLaunchKernelGGL(k_fwdweff, dim3(144), dim3(256), 0, stream,
                     word, W2, fwd, Wa, W3, partial);
  hipLaunchKernelGGL(k_fused, dim3(50, 8), dim3(256), 0, stream,
                     fmapH, W1h, fwd, partial, coefp);
  hipLaunchKernelGGL(k_pool, dim3(8, 5, 8), dim3(256), 0, stream, coefp, img, out);
  (void)in_sizes; (void)n_in; (void)out_size; (void)ws_size;
}